// Round 4
// baseline (122.000 us; speedup 1.0000x reference)
//
#include <hip/hip_runtime.h>
#include <stdint.h>

// Problem constants (fixed by reference)
#define N_IMG   16
#define C_IN    256
#define H_IN    32
#define W_IN    32
#define OH      30
#define OW      30
#define K_SEL   1152                   // C*KH*KW/2
#define OUTC    512
#define RY_TOT  (N_IMG * OH)           // 480 (n,y) rows
#define M_HAT   (RY_TOT * 32)          // 15360 = padded M (ow 30 -> 32)
#define X_ELEMS (N_IMG * C_IN * H_IN * W_IN)   // 4194304
#define OUT_SP  (OH * OW)              // 900
#define CHW     (C_IN * H_IN * W_IN)   // 262144

#define TO      128                    // o-tile
#define TM      64                     // m-tile = 2 ry rows x 32 xw
#define NMT     (M_HAT / TM)           // 240
#define NOT     (OUTC / TO)            // 4
#define BSTR    40                     // Bs row stride (shorts): 80B rows -> 16B-aligned b128
#define KITER   (K_SEL / 32)           // 36

typedef float f32x4  __attribute__((ext_vector_type(4)));
typedef short bf16x8 __attribute__((ext_vector_type(8)));   // 8 bf16 = 4 VGPRs

__device__ __forceinline__ unsigned short f2bf(float f) {   // fp32 -> bf16 RNE
    unsigned int u = __float_as_uint(f);
    u += 0x7FFFu + ((u >> 16) & 1u);
    return (unsigned short)(u >> 16);
}

// async global->LDS, 16B/lane; LDS dst wave-uniform base, HW adds lane*16.
__device__ __forceinline__ void gl_lds16(const void* g, void* lds) {
    __builtin_amdgcn_global_load_lds(
        (const __attribute__((address_space(1))) unsigned int*)g,
        (__attribute__((address_space(3))) unsigned int*)lds,
        16, 0, 0);
}

// ---------------------------------------------------------------------------
// Prep: koff decode + coalesced LDS-tile transpose w(K_SEL x OUTC fp32) ->
// wT(OUTC x K_SEL bf16). Grid (36 s-tiles, 16 o-tiles) x 256 thr.
// ---------------------------------------------------------------------------
__global__ void prep_kernel(const int* __restrict__ idx, const float* __restrict__ w,
                            int* __restrict__ koff, unsigned short* __restrict__ wT) {
    __shared__ float tile[32][33];                 // +1 pad: phase1 conflict-free
    const int bx = blockIdx.x, by = blockIdx.y, t = threadIdx.x;

    if (by == 0) {                                 // fold koff decode into first row
        int k = bx * 256 + t;
        if (k < K_SEL) {
            int v = idx[k];
            int c = v / 9, rem = v - c * 9;
            int i = rem / 3, j = rem - i * 3;
            koff[k] = c * (H_IN * W_IN) + i * W_IN + j;
        }
    }
    const int s0 = bx * 32, o0 = by * 32;
    const int oc = t & 31, sg = t >> 5;
#pragma unroll
    for (int i = 0; i < 4; ++i) {                  // coalesced 128B reads along o
        int sl = sg * 4 + i;
        tile[sl][oc] = w[(s0 + sl) * OUTC + o0 + oc];
    }
    __syncthreads();
    const int ol = t >> 3, sq = t & 7;             // write along s: coalesced
    unsigned int u0 = (unsigned int)f2bf(tile[sq * 4 + 0][ol]) |
                      ((unsigned int)f2bf(tile[sq * 4 + 1][ol]) << 16);
    unsigned int u1 = (unsigned int)f2bf(tile[sq * 4 + 2][ol]) |
                      ((unsigned int)f2bf(tile[sq * 4 + 3][ol]) << 16);
    uint2 pk; pk.x = u0; pk.y = u1;
    *reinterpret_cast<uint2*>(&wT[(size_t)(o0 + ol) * K_SEL + s0 + sq * 4]) = pk;
}

// ---------------------------------------------------------------------------
// Fused GEMM: out[n,o,y,x] = sum_k wT[o][k] * x[n, koff[k] + y*32 + xw]
// Tile 128o x 64m, BK=32, 960 blocks.
// R4 theory: R1/R3 nulls show the cost is PHASE SERIALIZATION (all pipes
// ~30% busy; waves barrier-locked to the same phase). Decouple:
//  * As is wave-private -> SINGLE buffer, NO barrier: frag reads ->
//    lgkmcnt(0) -> gl_lds overwrite (intra-wave ordering only).
//  * Bs QUAD-buffered, packed 2 tiles ahead -> all cross-wave RAW/WAR
//    distances >= 2 iters -> barrier every 2 k-steps (36 -> 18), waves
//    free to skew and interleave VALU/LDS/MFMA phases.
//  * s_setprio(1) around MFMA (waves now skewed -> scheduler has roles).
//  * xw clamp (min(xw,29)) replaces per-gather min: max address proven
//    == X_ELEMS-1, saves 8 VALU/thread-iter.
//  * manual unroll x4: every Bs/v slot index is a literal (no scratch).
// Counted waits: vmcnt(8) at iter top (prev iter's 2 gl_lds done -> As
// ready), vmcnt(10) before pack (prev iter's 8 gathers done).
// ---------------------------------------------------------------------------
__global__ __launch_bounds__(256, 4)
void gemm_kernel(const unsigned short* __restrict__ wT, const float* __restrict__ x,
                 const int* __restrict__ koff, float* __restrict__ out) {
    __shared__ __align__(16) unsigned short As[TO * 32];       // single, wave-private rows
    __shared__ __align__(16) unsigned short Bs[4][TM * BSTR];  // quad buffer
    __shared__ int koS[K_SEL];

    const int t    = threadIdx.x;
    const int wave = t >> 6;
    const int lane = t & 63;
    const int quad = lane >> 4;
    const int lo   = lane & 15;

    const int bid = blockIdx.x;
    const int mt  = bid % NMT;
    const int ot  = bid / NMT;
    const int oBase = ot * TO;
    const int mBase = mt * TM;

    for (int i = t; i < K_SEL; i += 256) koS[i] = koff[i];

    const int xw  = t & 31;                        // spatial lane within ry row
    const int xwc = min(xw, 29);                   // clamp: all gathers in-bounds
    int basex[2];
#pragma unroll
    for (int ry = 0; ry < 2; ++ry) {
        int ryg = mt * 2 + ry;
        int n = ryg / 30, y = ryg - n * 30;
        basex[ry] = n * CHW + y * W_IN + xwc;
    }

    const int kq4 = t >> 5;                        // 0..7 -> 4 k's each
    const int ks  = kq4 * 4;

    // A staging: each wave owns 32 o-rows; 2 gl_lds16 of 1KB per k-tile.
    // Source pre-swizzled so linear LDS holds chunk c ^ ((row>>1)&3).
    const int lrow = lane >> 2, csw = (lane & 3) ^ ((lrow >> 1) & 3);
    const unsigned short* wrow0 = wT + (size_t)(oBase + wave * 32 + lrow) * K_SEL + csw * 8;
    const unsigned short* wrow1 = wT + (size_t)(oBase + wave * 32 + 16 + lrow) * K_SEL + csw * 8;
    unsigned short* lA0 = &As[(wave * 32) * 32];
    unsigned short* lA1 = lA0 + 16 * 32;

    // Loop-invariant addresses (same XOR applied on the chunk index).
    const int aswz = quad ^ ((lo >> 1) & 3);
    const unsigned short* aB = &As[(wave * 32 + lo) * 32 + aswz * 8];
    const unsigned short* bB[4] = {
        &Bs[0][lo * BSTR + quad * 8], &Bs[1][lo * BSTR + quad * 8],
        &Bs[2][lo * BSTR + quad * 8], &Bs[3][lo * BSTR + quad * 8] };
    unsigned short* bW[4] = {
        &Bs[0][xw * BSTR + ks], &Bs[1][xw * BSTR + ks],
        &Bs[2][xw * BSTR + ks], &Bs[3][xw * BSTR + ks] };

    __syncthreads();                               // koS ready (one-time drain ok)

    f32x4 acc[2][4] = {};
    float v[2][2][4];                              // 2 rolling gather slots

    // ---- prologue: stage t0; gather t0,t1,t2; pack t0->Bs[0], t1->Bs[1] ----
    gl_lds16(wrow0, lA0);                          // VMEM 1-2
    gl_lds16(wrow1, lA1);
#pragma unroll
    for (int tl = 0; tl < 2; ++tl) {               // gathers t0 (VMEM 3-10), t1 (11-18)
        int4 k4 = *(const int4*)&koS[tl * 32 + ks];
#pragma unroll
        for (int ry = 0; ry < 2; ++ry)
#pragma unroll
            for (int j = 0; j < 4; ++j)
                v[tl][ry][j] = x[basex[ry] + ((const int*)&k4)[j]];
    }
    asm volatile("s_waitcnt vmcnt(8)" ::: "memory");   // gl_lds(t0) + gathers(t0) done
#pragma unroll
    for (int ry = 0; ry < 2; ++ry) {               // pack t0 -> Bs[0]
        unsigned int u0 = (unsigned int)f2bf(v[0][ry][0]) |
                          ((unsigned int)f2bf(v[0][ry][1]) << 16);
        unsigned int u1 = (unsigned int)f2bf(v[0][ry][2]) |
                          ((unsigned int)f2bf(v[0][ry][3]) << 16);
        uint2 pk; pk.x = u0; pk.y = u1;
        *reinterpret_cast<uint2*>(bW[0] + ry * 32 * BSTR) = pk;
    }
    {                                              // gather t2 -> v[0] (VMEM 8 more)
        int4 k4 = *(const int4*)&koS[2 * 32 + ks];
#pragma unroll
        for (int ry = 0; ry < 2; ++ry)
#pragma unroll
            for (int j = 0; j < 4; ++j)
                v[0][ry][j] = x[basex[ry] + ((const int*)&k4)[j]];
    }
    asm volatile("s_waitcnt vmcnt(8)" ::: "memory");   // gathers(t1) done
#pragma unroll
    for (int ry = 0; ry < 2; ++ry) {               // pack t1 -> Bs[1]
        unsigned int u0 = (unsigned int)f2bf(v[1][ry][0]) |
                          ((unsigned int)f2bf(v[1][ry][1]) << 16);
        unsigned int u1 = (unsigned int)f2bf(v[1][ry][2]) |
                          ((unsigned int)f2bf(v[1][ry][3]) << 16);
        uint2 pk; pk.x = u0; pk.y = u1;
        *reinterpret_cast<uint2*>(bW[1] + ry * 32 * BSTR) = pk;
    }
    asm volatile("s_waitcnt lgkmcnt(0)" ::: "memory");
    __builtin_amdgcn_s_barrier();                  // Bs[0], Bs[1] visible

    // ---- main loop: manual x4 unroll, barrier every 2 k-steps ----
    // iter kt: read As(kt)+Bs[kt&3]; gl_lds(kt+1)->As; gather(kt+3)->v[(kt+1)&1];
    //          pack(kt+2) from v[kt&1] -> Bs[(kt+2)&3]; 8 MFMA.
#define KSTEP(KT, C, VR, VW) do {                                              \
    asm volatile("s_waitcnt vmcnt(8)" ::: "memory"); /* As(kt) staged */       \
    bf16x8 a0_ = *(const bf16x8*)(aB);                                         \
    bf16x8 a1_ = *(const bf16x8*)(aB + 16 * 32);                               \
    bf16x8 b0_ = *(const bf16x8*)(bB[C]);                                      \
    bf16x8 b1_ = *(const bf16x8*)(bB[C] + 16 * BSTR);                          \
    bf16x8 b2_ = *(const bf16x8*)(bB[C] + 32 * BSTR);                          \
    bf16x8 b3_ = *(const bf16x8*)(bB[C] + 48 * BSTR);                          \
    const int kg_ = ((KT) + 3 < KITER ? (KT) + 3 : KITER - 1) * 32;            \
    int4 k4_ = *(const int4*)&koS[kg_ + ks];                                   \
    asm volatile("s_waitcnt lgkmcnt(0)" ::: "memory"); /* frags+k4 in regs */  \
    __builtin_amdgcn_sched_barrier(0);                                         \
    const int k1_ = ((KT) + 1 < KITER ? (KT) + 1 : KITER - 1) * 32;            \
    gl_lds16(wrow0 + k1_, lA0);                    /* safe: As consumed */     \
    gl_lds16(wrow1 + k1_, lA1);                                                \
    _Pragma("unroll")                                                          \
    for (int ry = 0; ry < 2; ++ry)                                             \
        _Pragma("unroll")                                                      \
        for (int j = 0; j < 4; ++j)                                            \
            v[VW][ry][j] = x[basex[ry] + ((const int*)&k4_)[j]];               \
    asm volatile("s_waitcnt vmcnt(10)" ::: "memory"); /* prev gathers done */  \
    _Pragma("unroll")                                                          \
    for (int ry = 0; ry < 2; ++ry) {                                           \
        unsigned int u0_ = (unsigned int)f2bf(v[VR][ry][0]) |                  \
                           ((unsigned int)f2bf(v[VR][ry][1]) << 16);           \
        unsigned int u1_ = (unsigned int)f2bf(v[VR][ry][2]) |                  \
                           ((unsigned int)f2bf(v[VR][ry][3]) << 16);           \
        uint2 pk_; pk_.x = u0_; pk_.y = u1_;                                   \
        *reinterpret_cast<uint2*>(bW[((C) + 2) & 3] + ry * 32 * BSTR) = pk_;   \
    }                                                                          \
    __builtin_amdgcn_s_setprio(1);                                             \
    acc[0][0] = __builtin_amdgcn_mfma_f32_16x16x32_bf16(a0_, b0_, acc[0][0], 0, 0, 0); \
    acc[0][1] = __builtin_amdgcn_mfma_f32_16x16x32_bf16(a0_, b1_, acc[0][1], 0, 0, 0); \
    acc[0][2] = __builtin_amdgcn_mfma_f32_16x16x32_bf16(a0_, b2_, acc[0][2], 0, 0, 0); \
    acc[0][3] = __builtin_amdgcn_mfma_f32_16x16x32_bf16(a0_, b3_, acc[0][3], 0, 0, 0); \
    acc[1][0] = __builtin_amdgcn_mfma_f32_16x16x32_bf16(a1_, b0_, acc[1][0], 0, 0, 0); \
    acc[1][1] = __builtin_amdgcn_mfma_f32_16x16x32_bf16(a1_, b1_, acc[1][1], 0, 0, 0); \
    acc[1][2] = __builtin_amdgcn_mfma_f32_16x16x32_bf16(a1_, b2_, acc[1][2], 0, 0, 0); \
    acc[1][3] = __builtin_amdgcn_mfma_f32_16x16x32_bf16(a1_, b3_, acc[1][3], 0, 0, 0); \
    __builtin_amdgcn_s_setprio(0);                                             \
} while (0)

    for (int kt0 = 0; kt0 < KITER; kt0 += 4) {
        KSTEP(kt0 + 0, 0, 0, 1);
        KSTEP(kt0 + 1, 1, 1, 0);
        asm volatile("s_waitcnt lgkmcnt(0)" ::: "memory");
        __builtin_amdgcn_s_barrier();              // packs(kt0+2,kt0+3) visible
        KSTEP(kt0 + 2, 2, 0, 1);
        KSTEP(kt0 + 3, 3, 1, 0);
        asm volatile("s_waitcnt lgkmcnt(0)" ::: "memory");
        __builtin_amdgcn_s_barrier();
    }
#undef KSTEP

    // Epilogue (verified R1 mapping): D row = o (quad*4+r), col = m (lane&15).
#pragma unroll
    for (int ns = 0; ns < 4; ++ns) {
        const int mh  = mBase + ns * 16 + lo;
        const int xwe = mh & 31;
        const int ryg = mh >> 5;
        const int n = ryg / 30, y = ryg - n * 30;
        if (xwe < OW) {
            const size_t ob = (size_t)n * (OUTC * OUT_SP) + (size_t)y * OW + xwe;
#pragma unroll
            for (int ms = 0; ms < 2; ++ms) {
                const int o0 = oBase + wave * 32 + ms * 16 + quad * 4;
#pragma unroll
                for (int r = 0; r < 4; ++r)
                    out[ob + (size_t)(o0 + r) * OUT_SP] = acc[ms][ns][r];
            }
        }
    }
}

// ---------------------------------------------------------------------------
extern "C" void kernel_launch(void* const* d_in, const int* in_sizes, int n_in,
                              void* d_out, int out_size, void* d_ws, size_t ws_size,
                              hipStream_t stream) {
    const float* x   = (const float*)d_in[0];
    const float* w   = (const float*)d_in[1];
    const int*   idx = (const int*)d_in[2];
    float*       out = (float*)d_out;

    // ws layout: koff 4608B | wT bf16 1179648B  (~1.2 MB total)
    char* ws = (char*)d_ws;
    int*            koff = (int*)ws;
    unsigned short* wT   = (unsigned short*)(ws + 4608);

    prep_kernel<<<dim3(K_SEL / 32, OUTC / 32), dim3(256), 0, stream>>>(idx, w, koff, wT);
    gemm_kernel<<<dim3(NMT * NOT), dim3(256), 0, stream>>>(wT, x, koff, out);
}